// Round 12
// baseline (105.751 us; speedup 1.0000x reference)
//
#include <hip/hip_runtime.h>
#include <hip/hip_fp16.h>

#define G_ 8
#define C_ 64
#define K_ 9
#define H_ 100
#define W_ 160
#define TW_ 8
#define TH_ 8
#define HALO_ 4
#define SW_ (TW_ + 2*HALO_)       // 16 staged cols
#define SH_ (TH_ + 2*HALO_)       // 16 staged rows
#define NREC_ (SW_ * SH_)         // 256 records
#define RECU_ 17                  // 136 B record stride in u64 (odd-8B -> bank rotate)
#define LDSU_ (NREC_ * RECU_)     // 4352 u64 = 34816 B -> 4 blocks/CU

// One block = (group g, 8x8 pixel tile), 256 threads = 4 waves, 4 blocks/CU.
// Phase A (pre-barrier): softmax + all 9 taps' packed f16 weights and record
// info into registers (overlaps staging). Staging: tile+halo f32->f16,
// 128 B/record, XOR-chunk swizzle, 136 B stride. Phase B: tight unrolled
// gather loop -- per tap: 4x ds_read_b128 + 4 perm-dups + 32 hfma2.
// NO runtime indexing of register arrays anywhere (R11 lesson: the fixup's
// mv[k] with runtime k spilled every array to scratch -> 248 MB of HBM
// writes). The rare out-of-box fixup recomputes everything from GLOBAL
// memory (runtime index on global pointers is fine).
__global__ __launch_bounds__(256, 4) void dcn_lds_kernel(
    const float* __restrict__ x,      // [H,W,G*C] f32
    const float* __restrict__ offset, // [H,W,G*K*2]
    const float* __restrict__ mask,   // [H,W,G*K]
    float* __restrict__ out)          // [H,W,G*C]
{
    __shared__ unsigned long long sm[LDSU_];
    const int bid = (int)blockIdx.x;
    const int g   = bid & 7;          // group
    const int t   = bid >> 3;         // 0..259 tile id (13 rows x 20 cols)
    const int th  = t / 20, twc = t % 20;
    const int h0  = th * TH_, w0 = twc * TW_;
    const int tid = (int)threadIdx.x;

    const int p   = tid >> 2;           // 0..63 pixel in tile
    const int q   = tid & 3;            // 32-B chunk index (16 channels)
    const int chb = q * 16;             // channel base
    const int hh  = h0 + (p >> 3);
    const int ww  = w0 + (p & 7);
    const bool live = (hh < H_);        // ragged bottom tile row
    const int pixg = (hh * W_ + ww) * G_ + g;

    // ---------------- phase A: softmax + per-tap weight/addr precompute ----
    float mmax = -1e30f, minv = 0.f;
    unsigned wp0[K_], wp1[K_], wi[K_];
    unsigned fb = 0;
    if (live) {
        const float* mptr = mask + (size_t)pixg * K_;
        float mv[K_];
#pragma unroll
        for (int k = 0; k < K_; ++k) { mv[k] = mptr[k]; mmax = fmaxf(mmax, mv[k]); }
        float msum = 0.f;
#pragma unroll
        for (int k = 0; k < K_; ++k) { mv[k] = __expf(mv[k] - mmax); msum += mv[k]; }
        minv = 1.f / msum;

        const float* optr = offset + (size_t)pixg * (K_ * 2);
#pragma unroll
        for (int k = 0; k < K_; ++k) {
            const float2 o2 = *(const float2*)(optr + 2 * k);
            const float lh = (float)(hh + k / 3 - 1) + o2.x;
            const float lw = (float)(ww + k % 3 - 1) + o2.y;
            const float fh0 = floorf(lh), fw0 = floorf(lw);
            const float ft = lh - fh0, gt = lw - fw0;
            const int hI = (int)fh0, wI = (int)fw0;
            const float m = mv[k] * minv;

            const float wh0 = (hI >= 0  && hI < H_    ) ? (1.f - ft) * m : 0.f;
            const float wh1 = (hI >= -1 && hI < H_ - 1) ? ft * m         : 0.f;
            const float cw0 = (wI >= 0  && wI < W_    ) ? (1.f - gt)     : 0.f;
            const float cw1 = (wI >= -1 && wI < W_ - 1) ? gt             : 0.f;
            __half2 wa = __floats2half2_rn(wh0 * cw0, wh0 * cw1);
            __half2 wb = __floats2half2_rn(wh1 * cw0, wh1 * cw1);

            const int hc0 = min(max(hI,     0), H_ - 1);
            const int hc1 = min(max(hI + 1, 0), H_ - 1);
            const int wc0 = min(max(wI,     0), W_ - 1);
            const int wc1 = min(max(wI + 1, 0), W_ - 1);

            const bool inbox = (hI >= h0 - HALO_) && (hI <= h0 + TH_ + HALO_ - 2) &&
                               (wI >= w0 - HALO_) && (wI <= w0 + TW_ + HALO_ - 2);

            unsigned ua = *(unsigned*)&wa;
            unsigned ub = *(unsigned*)&wb;
            int ri0 = hc0 - (h0 - HALO_), rj0 = wc0 - (w0 - HALO_);
            int dc  = wc1 - wc0, dr = hc1 - hc0;            // 0/1 each
            if (!inbox) {
                fb |= 1u << k;
                ua = 0u; ub = 0u;
                ri0 = min(max(ri0, 0), SH_ - 1);
                rj0 = min(max(rj0, 0), SW_ - 1);
                dc = 0; dr = 0;
            }
            wp0[k] = ua;
            wp1[k] = ub;
            wi[k]  = (unsigned)(ri0 * SW_ + rj0) | ((unsigned)dc << 16) | ((unsigned)dr << 17);
        }
    } else {
#pragma unroll
        for (int k = 0; k < K_; ++k) { wp0[k] = 0; wp1[k] = 0; wi[k] = 0; }
    }

    // ---------------- stage x tile (f32 -> f16, swizzled) ----------------
    // 256 recs x 8 sub-chunks = 2048 tasks = 8 x 256
#pragma unroll
    for (int it = 0; it < 8; ++it) {
        const int task = it * 256 + tid;
        const int rec = task >> 3, sub = task & 7;
        const int i = rec >> 4, j = rec & 15;        // SW_ == 16
        const int hs = h0 - HALO_ + i, ws = w0 - HALO_ + j;
        if (hs >= 0 && hs < H_ && ws >= 0 && ws < W_) {
            const float* src = x + (size_t)(hs * W_ + ws) * (G_ * C_) + g * C_ + sub * 8;
            const float4 A = *(const float4*)src;
            const float4 B = *(const float4*)(src + 4);
            __half2 p0 = __floats2half2_rn(A.x, A.y);
            __half2 p1 = __floats2half2_rn(A.z, A.w);
            __half2 p2 = __floats2half2_rn(B.x, B.y);
            __half2 p3 = __floats2half2_rn(B.z, B.w);
            const unsigned long long lo =
                ((unsigned long long)*(unsigned*)&p1 << 32) | *(unsigned*)&p0;
            const unsigned long long hi =
                ((unsigned long long)*(unsigned*)&p3 << 32) | *(unsigned*)&p2;
            const int c = sub >> 1, hsel = sub & 1;  // 32-B chunk, 16-B half
            const int base = rec * RECU_ + ((c ^ (rec & 3)) << 2) + hsel * 2;
            sm[base]     = lo;
            sm[base + 1] = hi;
        }
    }
    __syncthreads();

    if (!live) return;

    // ---------------- phase B: pure gather + FMA ----------------
    __half2 acc[3][8];
#pragma unroll
    for (int gr = 0; gr < 3; ++gr)
#pragma unroll
        for (int u = 0; u < 8; ++u) acc[gr][u] = __half2(__half(0.f), __half(0.f));

#pragma unroll
    for (int k = 0; k < K_; ++k) {
        const int gr = k / 3;                         // compile-time under unroll
        const unsigned info = wi[k];
        const int r00 = (int)(info & 0xffffu);
        const int dc  = (int)((info >> 16) & 1u);
        const int r10 = r00 + ((int)((info >> 17) & 1u) << 4);   // +dr*SW_
        const int r01 = r00 + dc;
        const int r11 = r10 + dc;

        const unsigned W00d = __builtin_amdgcn_perm(wp0[k], wp0[k], 0x01000100u);
        const unsigned W01d = __builtin_amdgcn_perm(wp0[k], wp0[k], 0x03020302u);
        const unsigned W10d = __builtin_amdgcn_perm(wp1[k], wp1[k], 0x01000100u);
        const unsigned W11d = __builtin_amdgcn_perm(wp1[k], wp1[k], 0x03020302u);

#define CORNER(REC, WTU)                                                      \
        {                                                                     \
            const __half2 WT = *(const __half2*)&(WTU);                       \
            const int b = (REC) * RECU_ + ((q ^ ((REC) & 3)) << 2);           \
            const unsigned long long qa = sm[b],     qb = sm[b + 1];          \
            const unsigned long long qc = sm[b + 2], qd = sm[b + 3];          \
            unsigned u32;                                                     \
            u32 = (unsigned)qa;         acc[gr][0] = __hfma2(*(__half2*)&u32, WT, acc[gr][0]); \
            u32 = (unsigned)(qa >> 32); acc[gr][1] = __hfma2(*(__half2*)&u32, WT, acc[gr][1]); \
            u32 = (unsigned)qb;         acc[gr][2] = __hfma2(*(__half2*)&u32, WT, acc[gr][2]); \
            u32 = (unsigned)(qb >> 32); acc[gr][3] = __hfma2(*(__half2*)&u32, WT, acc[gr][3]); \
            u32 = (unsigned)qc;         acc[gr][4] = __hfma2(*(__half2*)&u32, WT, acc[gr][4]); \
            u32 = (unsigned)(qc >> 32); acc[gr][5] = __hfma2(*(__half2*)&u32, WT, acc[gr][5]); \
            u32 = (unsigned)qd;         acc[gr][6] = __hfma2(*(__half2*)&u32, WT, acc[gr][6]); \
            u32 = (unsigned)(qd >> 32); acc[gr][7] = __hfma2(*(__half2*)&u32, WT, acc[gr][7]); \
        }
        CORNER(r00, W00d) CORNER(r01, W01d) CORNER(r10, W10d) CORNER(r11, W11d)
#undef CORNER
    }

    // ------- rare out-of-box fixup: recompute EVERYTHING from global -------
    // (runtime k only ever indexes global pointers -> no register-array
    //  scratch spill; mmax/minv are scalars)
    if (__builtin_expect(fb != 0, 0)) {
        const float* optr = offset + (size_t)pixg * (K_ * 2);
        const float* mptr = mask   + (size_t)pixg * K_;
        while (fb) {
            const int k = __ffs(fb) - 1; fb &= fb - 1;
            const float m = __expf(mptr[k] - mmax) * minv;
            const float2 o2 = *(const float2*)(optr + 2 * k);
            const float lh = (float)(hh + k / 3 - 1) + o2.x;
            const float lw = (float)(ww + k % 3 - 1) + o2.y;
            const float fh0 = floorf(lh), fw0 = floorf(lw);
            const float ft = lh - fh0, gt = lw - fw0;
            const int hI = (int)fh0, wI = (int)fw0;
            const float wh0 = (hI >= 0  && hI < H_    ) ? (1.f - ft) * m : 0.f;
            const float wh1 = (hI >= -1 && hI < H_ - 1) ? ft * m         : 0.f;
            const float cw0 = (wI >= 0  && wI < W_    ) ? (1.f - gt)     : 0.f;
            const float cw1 = (wI >= -1 && wI < W_ - 1) ? gt             : 0.f;
            const int hc0 = min(max(hI,     0), H_ - 1);
            const int hc1 = min(max(hI + 1, 0), H_ - 1);
            const int wc0 = min(max(wI,     0), W_ - 1);
            const int wc1 = min(max(wI + 1, 0), W_ - 1);
#define GCORNER(HC, WC, WF)                                                   \
            {                                                                 \
                const __half2 WT = __float2half2_rn(WF);                      \
                const float* s = x + (size_t)((HC) * W_ + (WC)) * (G_ * C_) + g * C_ + chb; \
                _Pragma("unroll")                                             \
                for (int u = 0; u < 4; ++u) {                                 \
                    const float4 v = *(const float4*)(s + u * 4);             \
                    __half2 e0 = __floats2half2_rn(v.x, v.y);                 \
                    __half2 e1 = __floats2half2_rn(v.z, v.w);                 \
                    acc[0][u*2]   = __hfma2(e0, WT, acc[0][u*2]);             \
                    acc[0][u*2+1] = __hfma2(e1, WT, acc[0][u*2+1]);           \
                }                                                             \
            }
            GCORNER(hc0, wc0, wh0 * cw0) GCORNER(hc0, wc1, wh0 * cw1)
            GCORNER(hc1, wc0, wh1 * cw0) GCORNER(hc1, wc1, wh1 * cw1)
#undef GCORNER
        }
    }

    // fold 3 f16 groups in f32, store 16 channels (4x float4, coalesced)
    float* op = out + (size_t)pixg * C_ + chb;
#pragma unroll
    for (int a = 0; a < 8; a += 2) {
        const float2 s0 = __half22float2(acc[0][a]);
        const float2 t1 = __half22float2(acc[1][a]);
        const float2 t2 = __half22float2(acc[2][a]);
        const float2 s1 = __half22float2(acc[0][a + 1]);
        const float2 t3 = __half22float2(acc[1][a + 1]);
        const float2 t4 = __half22float2(acc[2][a + 1]);
        float4 o;
        o.x = s0.x + t1.x + t2.x;
        o.y = s0.y + t1.y + t2.y;
        o.z = s1.x + t3.x + t4.x;
        o.w = s1.y + t3.y + t4.y;
        *(float4*)(op + a * 2) = o;
    }
}

extern "C" void kernel_launch(void* const* d_in, const int* in_sizes, int n_in,
                              void* d_out, int out_size, void* d_ws, size_t ws_size,
                              hipStream_t stream) {
    const float* x      = (const float*)d_in[0];
    const float* offset = (const float*)d_in[1];
    const float* mask   = (const float*)d_in[2];
    float* out          = (float*)d_out;

    // 13x20 tiles x 8 groups = 2080 blocks of 256 threads
    dcn_lds_kernel<<<2080, 256, 0, stream>>>(x, offset, mask, out);
}

// Round 13
// 36.515 us; speedup vs baseline: 2.8961x; 2.8961x over previous
//
#include <hip/hip_runtime.h>
#include <hip/hip_fp16.h>

#define G_ 8
#define C_ 64
#define K_ 9
#define H_ 100
#define W_ 160
#define TW_ 16
#define TH_ 8
#define HALO_ 4
#define SW_ (TW_ + 2*HALO_)       // 24 staged cols
#define SH_ (TH_ + 2*HALO_)       // 16 staged rows
#define NREC_ (SW_ * SH_)         // 384 records
#define RECU_ 17                  // 136 B record stride, in u64 units
#define LDSU_ (NREC_ * RECU_)     // 6528 u64 = 52224 B -> 3 blocks/CU

// R9 structure (best known: 41.5 us kernel) + ONE change: the 9 offset
// float2 loads and softmax pre-scaling are hoisted BEFORE the staging
// barrier (latency hides under staging). Phase B then has zero global
// accesses in the tap loop: weights (VALU from registers) -> 4x
// ds_read_b128 -> hfma2. All register arrays statically indexed
// (unrolled K-loop) -- no scratch (R11/R12 lesson).
__global__ __launch_bounds__(512, 6) void dcn_lds_kernel(
    const float* __restrict__ x,      // [H,W,G*C] f32
    const float* __restrict__ offset, // [H,W,G*K*2]
    const float* __restrict__ mask,   // [H,W,G*K]
    float* __restrict__ out)          // [H,W,G*C]
{
    __shared__ unsigned long long sm[LDSU_];
    const int bid = (int)blockIdx.x;
    const int g   = bid & 7;          // group -> XCD affinity (round-robin)
    const int t   = bid >> 3;         // 0..129 tile id
    const int th  = t / 10, twc = t % 10;
    const int h0  = th * TH_, w0 = twc * TW_;
    const int tid = (int)threadIdx.x;

    // ---- per-thread pixel/channel mapping (compute phase) ----
    const int p   = tid >> 2;           // 0..127 pixel in tile
    const int q   = tid & 3;            // channel quarter (32-B chunk)
    const int chb = q * 16;             // channel base
    const int hh  = h0 + (p >> 4);
    const int ww  = w0 + (p & 15);
    const bool live = (hh < H_);        // ragged bottom tile
    const int pixg = (hh * W_ + ww) * G_ + g;

    // ---- softmax + offset loads hoisted BEFORE barrier ----
    float mv[K_];          // pre-scaled softmax weights (mv[k] = softmax_k)
    float2 ov[K_];         // offsets
    if (live) {
        const float* mptr = mask + (size_t)pixg * K_;
        float mmax = -1e30f;
#pragma unroll
        for (int k = 0; k < K_; ++k) { mv[k] = mptr[k]; mmax = fmaxf(mmax, mv[k]); }
        float msum = 0.f;
#pragma unroll
        for (int k = 0; k < K_; ++k) { mv[k] = __expf(mv[k] - mmax); msum += mv[k]; }
        const float minv = 1.f / msum;
#pragma unroll
        for (int k = 0; k < K_; ++k) mv[k] *= minv;

        const float* optr = offset + (size_t)pixg * (K_ * 2);
#pragma unroll
        for (int k = 0; k < K_; ++k) ov[k] = *(const float2*)(optr + 2 * k);
    } else {
#pragma unroll
        for (int k = 0; k < K_; ++k) { mv[k] = 0.f; ov[k] = make_float2(0.f, 0.f); }
    }

    // ---------------- stage x tile (f32 -> f16, swizzled) ----------------
#pragma unroll
    for (int it = 0; it < (NREC_ * 8) / 512; ++it) {
        const int task = it * 512 + tid;
        const int rec = task >> 3, sub = task & 7;   // sub = 8-float chunk
        const int i = rec / SW_, j = rec - i * SW_;
        const int hs = h0 - HALO_ + i, ws = w0 - HALO_ + j;
        if (hs >= 0 && hs < H_ && ws >= 0 && ws < W_) {
            const float* src = x + (size_t)(hs * W_ + ws) * (G_ * C_) + g * C_ + sub * 8;
            const float4 A = *(const float4*)src;
            const float4 B = *(const float4*)(src + 4);
            __half2 p0 = __floats2half2_rn(A.x, A.y);
            __half2 p1 = __floats2half2_rn(A.z, A.w);
            __half2 p2 = __floats2half2_rn(B.x, B.y);
            __half2 p3 = __floats2half2_rn(B.z, B.w);
            const unsigned long long lo =
                ((unsigned long long)*(unsigned*)&p1 << 32) | *(unsigned*)&p0;
            const unsigned long long hi =
                ((unsigned long long)*(unsigned*)&p3 << 32) | *(unsigned*)&p2;
            const int c = sub >> 1, hsel = sub & 1;  // 32-B chunk, 16-B half
            const int base = rec * RECU_ + ((c ^ (rec & 3)) << 2) + hsel * 2;
            sm[base]     = lo;
            sm[base + 1] = hi;
        }
    }
    __syncthreads();

    if (!live) return;

    // ---------------- phase B: weights from regs + LDS gather -------------
    __half2 acc[3][8];
#pragma unroll
    for (int gr = 0; gr < 3; ++gr)
#pragma unroll
        for (int u = 0; u < 8; ++u) acc[gr][u] = __half2(__half(0.f), __half(0.f));

#pragma unroll
    for (int k = 0; k < K_; ++k) {
        const int gr = k / 3;
        const float lh = (float)(hh + k / 3 - 1) + ov[k].x;
        const float lw = (float)(ww + k % 3 - 1) + ov[k].y;
        const float fh0 = floorf(lh), fw0 = floorf(lw);
        const float ft = lh - fh0, gt = lw - fw0;
        const int hI = (int)fh0, wI = (int)fw0;
        const float m = mv[k];

        const float wh0 = (hI >= 0  && hI < H_    ) ? (1.f - ft) * m : 0.f;
        const float wh1 = (hI >= -1 && hI < H_ - 1) ? ft * m         : 0.f;
        const float cw0 = (wI >= 0  && wI < W_    ) ? (1.f - gt)     : 0.f;
        const float cw1 = (wI >= -1 && wI < W_ - 1) ? gt             : 0.f;
        const __half2 W00 = __float2half2_rn(wh0 * cw0);
        const __half2 W01 = __float2half2_rn(wh0 * cw1);
        const __half2 W10 = __float2half2_rn(wh1 * cw0);
        const __half2 W11 = __float2half2_rn(wh1 * cw1);

        const int hc0 = min(max(hI,     0), H_ - 1);
        const int hc1 = min(max(hI + 1, 0), H_ - 1);
        const int wc0 = min(max(wI,     0), W_ - 1);
        const int wc1 = min(max(wI + 1, 0), W_ - 1);

        // both corners (pre-clamp) inside staged halo box?
        const bool inbox = (hI >= h0 - HALO_) && (hI <= h0 + TH_ + HALO_ - 2) &&
                           (wI >= w0 - HALO_) && (wI <= w0 + TW_ + HALO_ - 2);

        if (inbox) {
            const int ri0 = hc0 - (h0 - HALO_), ri1 = hc1 - (h0 - HALO_);
            const int rj0 = wc0 - (w0 - HALO_), rj1 = wc1 - (w0 - HALO_);
            const int r00 = ri0 * SW_ + rj0, r01 = ri0 * SW_ + rj1;
            const int r10 = ri1 * SW_ + rj0, r11 = ri1 * SW_ + rj1;

#define CORNER(REC, WT)                                                       \
            {                                                                 \
                const int b = (REC) * RECU_ + ((q ^ ((REC) & 3)) << 2);       \
                const unsigned long long qa = sm[b],     qb = sm[b + 1];      \
                const unsigned long long qc = sm[b + 2], qd = sm[b + 3];      \
                unsigned u32;                                                 \
                u32 = (unsigned)qa;         acc[gr][0] = __hfma2(*(__half2*)&u32, (WT), acc[gr][0]); \
                u32 = (unsigned)(qa >> 32); acc[gr][1] = __hfma2(*(__half2*)&u32, (WT), acc[gr][1]); \
                u32 = (unsigned)qb;         acc[gr][2] = __hfma2(*(__half2*)&u32, (WT), acc[gr][2]); \
                u32 = (unsigned)(qb >> 32); acc[gr][3] = __hfma2(*(__half2*)&u32, (WT), acc[gr][3]); \
                u32 = (unsigned)qc;         acc[gr][4] = __hfma2(*(__half2*)&u32, (WT), acc[gr][4]); \
                u32 = (unsigned)(qc >> 32); acc[gr][5] = __hfma2(*(__half2*)&u32, (WT), acc[gr][5]); \
                u32 = (unsigned)qd;         acc[gr][6] = __hfma2(*(__half2*)&u32, (WT), acc[gr][6]); \
                u32 = (unsigned)(qd >> 32); acc[gr][7] = __hfma2(*(__half2*)&u32, (WT), acc[gr][7]); \
            }
            CORNER(r00, W00) CORNER(r01, W01) CORNER(r10, W10) CORNER(r11, W11)
#undef CORNER
        } else {
            // rare (P ~5e-4 per tap): direct global f32 loads at clamped coords
#define GCORNER(HC, WC, WT)                                                   \
            {                                                                 \
                const float* s = x + (size_t)((HC) * W_ + (WC)) * (G_ * C_) + g * C_ + chb; \
                _Pragma("unroll")                                             \
                for (int u = 0; u < 4; ++u) {                                 \
                    const float4 v = *(const float4*)(s + u * 4);             \
                    __half2 e0 = __floats2half2_rn(v.x, v.y);                 \
                    __half2 e1 = __floats2half2_rn(v.z, v.w);                 \
                    acc[gr][u*2]   = __hfma2(e0, (WT), acc[gr][u*2]);         \
                    acc[gr][u*2+1] = __hfma2(e1, (WT), acc[gr][u*2+1]);       \
                }                                                             \
            }
            GCORNER(hc0, wc0, W00) GCORNER(hc0, wc1, W01)
            GCORNER(hc1, wc0, W10) GCORNER(hc1, wc1, W11)
#undef GCORNER
        }
    }

    // fold 3 f16 groups in f32, store 16 channels (4x float4, coalesced)
    float* op = out + (size_t)pixg * C_ + chb;
#pragma unroll
    for (int a = 0; a < 8; a += 2) {
        const float2 s0 = __half22float2(acc[0][a]);
        const float2 t1 = __half22float2(acc[1][a]);
        const float2 t2 = __half22float2(acc[2][a]);
        const float2 s1 = __half22float2(acc[0][a + 1]);
        const float2 t3 = __half22float2(acc[1][a + 1]);
        const float2 t4 = __half22float2(acc[2][a + 1]);
        float4 o;
        o.x = s0.x + t1.x + t2.x;
        o.y = s0.y + t1.y + t2.y;
        o.z = s1.x + t3.x + t4.x;
        o.w = s1.y + t3.y + t4.y;
        *(float4*)(op + a * 2) = o;
    }
}

extern "C" void kernel_launch(void* const* d_in, const int* in_sizes, int n_in,
                              void* d_out, int out_size, void* d_ws, size_t ws_size,
                              hipStream_t stream) {
    const float* x      = (const float*)d_in[0];
    const float* offset = (const float*)d_in[1];
    const float* mask   = (const float*)d_in[2];
    float* out          = (float*)d_out;

    // tiles: 13 rows (ceil(100/8)) x 10 cols (160/16) x 8 groups = 1040 blocks
    dcn_lds_kernel<<<1040, 512, 0, stream>>>(x, offset, mask, out);
}